// Round 5
// baseline (3088.500 us; speedup 1.0000x reference)
//
#include <hip/hip_runtime.h>
#include <hip/hip_bf16.h>

// Problem constants
#define BB 16
#define SS 512
#define DD 768
#define HH 8
#define VV 100
#define FF 2048
#define LL 6
#define DHH 96
#define TT (BB * SS)  // 8192 token rows
#define BH (BB * HH)  // 128 (batch,head) pairs

typedef __bf16 bf16x8 __attribute__((ext_vector_type(8)));
typedef float f32x4 __attribute__((ext_vector_type(4)));
typedef __hip_bfloat16 bf16_t;

// async global->LDS, 16B per lane; deposit = wave-uniform lds base + lane*16
__device__ __forceinline__ void load_lds16(const void* g, void* l) {
    __builtin_amdgcn_global_load_lds(
        (const __attribute__((address_space(1))) void*)g,
        (__attribute__((address_space(3))) void*)l, 16, 0, 0);
}

// ---------------------------------------------------------------------------
// fp32 -> bf16 conversion (grid-stride)
// ---------------------------------------------------------------------------
__global__ void cvt_kernel(const float* __restrict__ s, bf16_t* __restrict__ d, int n) {
    int i = blockIdx.x * blockDim.x + threadIdx.x;
    int stride = gridDim.x * blockDim.x;
    for (; i < n; i += stride) d[i] = __float2bfloat16(s[i]);
}

__global__ void fill_zero_kernel(uint4* __restrict__ p, int n) {
    int i = blockIdx.x * blockDim.x + threadIdx.x;
    if (i < n) p[i] = uint4{0u, 0u, 0u, 0u};
}

// out_w [100,768] -> padded bf16 [128,768] (rows 100..127 zero)
__global__ void pad_wout_kernel(const float* __restrict__ s, bf16_t* __restrict__ d) {
    int i = blockIdx.x * blockDim.x + threadIdx.x;  // exactly 128*768 threads
    int row = i / DD;
    d[i] = (row < VV) ? __float2bfloat16(s[i]) : __float2bfloat16(0.f);
}

// ---------------------------------------------------------------------------
// Embedding: x[t,:] = tok_emb[target[t],:] + pos_emb[s,:]  (writes fp32 + bf16)
// ---------------------------------------------------------------------------
__global__ void embed_kernel(const int* __restrict__ target,
                             const float* __restrict__ tok_emb,
                             const float* __restrict__ pos_emb,
                             float* __restrict__ x, bf16_t* __restrict__ xb) {
    int t = blockIdx.x;            // 0..8191
    int s = t & (SS - 1);
    int tok = target[t];
    const float* te = tok_emb + (size_t)tok * DD;
    const float* pe = pos_emb + (size_t)s * DD;
    for (int d = threadIdx.x; d < DD; d += blockDim.x) {
        float v = te[d] + pe[d];
        x[(size_t)t * DD + d] = v;
        xb[(size_t)t * DD + d] = __float2bfloat16(v);
    }
}

// ---------------------------------------------------------------------------
// Collapsed cross-attention, batched over all 16 latents per weight read.
// ---------------------------------------------------------------------------
__global__ __launch_bounds__(256) void cvmm_kernel(
    const float* __restrict__ in, int in_per_layer,
    const float* __restrict__ Wbase, size_t w_stride, size_t w_off,
    const float* __restrict__ bbase, size_t b_stride, size_t b_off,
    float* __restrict__ outp) {
    const int jc = blockIdx.x;
    const int layer = blockIdx.y;
    __shared__ float inb[BB][DD + 4];
    const int tid = threadIdx.x;
    const float* ip = in + (size_t)layer * in_per_layer;
    for (int idx = tid; idx < BB * DD; idx += 256) {
        int b = idx / DD, d = idx - b * DD;
        inb[b][d] = ip[(size_t)b * DD + d];
    }
    __syncthreads();
    const int j = jc * 16 + (tid >> 4);
    const int b = tid & 15;
    const float4* w4 = reinterpret_cast<const float4*>(
        Wbase + (size_t)layer * w_stride + w_off + (size_t)j * DD);
    const float4* i4 = reinterpret_cast<const float4*>(&inb[b][0]);
    float a = 0.f;
#pragma unroll 4
    for (int d = 0; d < DD / 4; ++d) {
        float4 w = w4[d], xv = i4[d];
        a += w.x * xv.x + w.y * xv.y + w.z * xv.z + w.w * xv.w;
    }
    a += bbase[(size_t)layer * b_stride + b_off + j];
    outp[((size_t)layer * BB + b) * DD + j] = a;
}

// ---------------------------------------------------------------------------
// bf16 MFMA GEMM: C[M,N] = A[M,K] @ W[N,K]^T + bias (+resid) (+relu)
// 128x128 tile, BK=64, 256 threads = 4 waves, each wave 64x64 (4x4 mfma tiles).
// Staging via global_load_lds width=16 (m97), XOR swizzle on the global side.
// __launch_bounds__(256,5): 5 blocks/CU (LDS 32KB x 5 = 160KB exactly; VGPR 60
// <= 102 budget). At 3 blocks/CU the barrier drain idled the CU
// (MfmaUtil 18%, Occ 21% measured R4); 5 blocks overlap across barriers.
// ---------------------------------------------------------------------------
template <bool RELU, bool BOUT, bool RES>
__global__ __launch_bounds__(256, 5) void gemm_bt(
    const bf16_t* __restrict__ A, const bf16_t* __restrict__ W,
    const float* __restrict__ bias, const float* __restrict__ resid,
    float* __restrict__ Cf, bf16_t* __restrict__ Cb,
    int K, int ldc, int Nreal) {
    __shared__ uint4 As4[128 * 8];
    __shared__ uint4 Bs4[128 * 8];
    const int m0 = blockIdx.y * 128;
    const int n0 = blockIdx.x * 128;
    const int lane = threadIdx.x & 63, wave = threadIdx.x >> 6;
    const int wr = wave >> 1, wc = wave & 1;
    const int r = lane & 15, q = lane >> 4;

    f32x4 acc[4][4];
#pragma unroll
    for (int i = 0; i < 4; ++i)
#pragma unroll
        for (int j = 0; j < 4; ++j) acc[i][j] = f32x4{0.f, 0.f, 0.f, 0.f};

    for (int k0 = 0; k0 < K; k0 += 64) {
#pragma unroll
        for (int it = 0; it < 4; ++it) {
            int base = it * 256 + wave * 64;  // wave-uniform LDS chunk base
            int c = base + lane;
            int row = c >> 3, pc = c & 7;
            int kc = pc ^ (row & 7);
            load_lds16(A + (size_t)(m0 + row) * K + k0 + kc * 8, &As4[base]);
            load_lds16(W + (size_t)(n0 + row) * K + k0 + kc * 8, &Bs4[base]);
        }
        __syncthreads();
#pragma unroll
        for (int kk = 0; kk < 2; ++kk) {
            bf16x8 af[4], bfr[4];
            int lc = kk * 4 + q;
#pragma unroll
            for (int i = 0; i < 4; ++i) {
                int rowA = wr * 64 + i * 16 + r;
                af[i] = *reinterpret_cast<const bf16x8*>(&As4[rowA * 8 + (lc ^ (rowA & 7))]);
                int rowB = wc * 64 + i * 16 + r;
                bfr[i] = *reinterpret_cast<const bf16x8*>(&Bs4[rowB * 8 + (lc ^ (rowB & 7))]);
            }
#pragma unroll
            for (int i = 0; i < 4; ++i)
#pragma unroll
                for (int j = 0; j < 4; ++j)
                    acc[i][j] = __builtin_amdgcn_mfma_f32_16x16x32_bf16(af[i], bfr[j], acc[i][j], 0, 0, 0);
        }
        __syncthreads();
    }

#pragma unroll
    for (int i = 0; i < 4; ++i) {
#pragma unroll
        for (int j = 0; j < 4; ++j) {
            int cc = n0 + wc * 64 + j * 16 + r;
            if (cc < Nreal) {
                float bv = bias[cc];
#pragma unroll
                for (int reg = 0; reg < 4; ++reg) {
                    int rr = m0 + wr * 64 + i * 16 + q * 4 + reg;
                    float v = acc[i][j][reg] + bv;
                    if (RES) v += resid[(size_t)rr * ldc + cc];
                    if (RELU) v = fmaxf(v, 0.f);
                    if (BOUT) Cb[(size_t)rr * ldc + cc] = __float2bfloat16(v);
                    else Cf[(size_t)rr * ldc + cc] = v;
                }
            }
        }
    }
}

// ---------------------------------------------------------------------------
// QKV projection GEMM with head-scatter epilogue.
// Writes: Qh [bh][512][128] bf16 (scaled by 1/sqrt(96), cols 96..127 pre-zeroed)
//         Kh [bh][512][128] bf16
//         Vt [bh][128][512] bf16 (transposed; rows 96..127 unused garbage)
// ---------------------------------------------------------------------------
__global__ __launch_bounds__(256, 5) void gemm_qkv(
    const bf16_t* __restrict__ A, const bf16_t* __restrict__ W,
    const float* __restrict__ bias,
    bf16_t* __restrict__ Qh, bf16_t* __restrict__ Kh, bf16_t* __restrict__ Vt) {
    __shared__ uint4 As4[128 * 8];
    __shared__ uint4 Bs4[128 * 8];
    const int m0 = blockIdx.y * 128;
    const int n0 = blockIdx.x * 128;
    const int lane = threadIdx.x & 63, wave = threadIdx.x >> 6;
    const int wr = wave >> 1, wc = wave & 1;
    const int r = lane & 15, q = lane >> 4;
    const int K = DD;

    f32x4 acc[4][4];
#pragma unroll
    for (int i = 0; i < 4; ++i)
#pragma unroll
        for (int j = 0; j < 4; ++j) acc[i][j] = f32x4{0.f, 0.f, 0.f, 0.f};

    for (int k0 = 0; k0 < K; k0 += 64) {
#pragma unroll
        for (int it = 0; it < 4; ++it) {
            int base = it * 256 + wave * 64;
            int c = base + lane;
            int row = c >> 3, pc = c & 7;
            int kc = pc ^ (row & 7);
            load_lds16(A + (size_t)(m0 + row) * K + k0 + kc * 8, &As4[base]);
            load_lds16(W + (size_t)(n0 + row) * K + k0 + kc * 8, &Bs4[base]);
        }
        __syncthreads();
#pragma unroll
        for (int kk = 0; kk < 2; ++kk) {
            bf16x8 af[4], bfr[4];
            int lc = kk * 4 + q;
#pragma unroll
            for (int i = 0; i < 4; ++i) {
                int rowA = wr * 64 + i * 16 + r;
                af[i] = *reinterpret_cast<const bf16x8*>(&As4[rowA * 8 + (lc ^ (rowA & 7))]);
                int rowB = wc * 64 + i * 16 + r;
                bfr[i] = *reinterpret_cast<const bf16x8*>(&Bs4[rowB * 8 + (lc ^ (rowB & 7))]);
            }
#pragma unroll
            for (int i = 0; i < 4; ++i)
#pragma unroll
                for (int j = 0; j < 4; ++j)
                    acc[i][j] = __builtin_amdgcn_mfma_f32_16x16x32_bf16(af[i], bfr[j], acc[i][j], 0, 0, 0);
        }
        __syncthreads();
    }

    const float scale = 0.10206207261596575f;  // 1/sqrt(96)
#pragma unroll
    for (int i = 0; i < 4; ++i) {
#pragma unroll
        for (int j = 0; j < 4; ++j) {
            int cc = n0 + wc * 64 + j * 16 + r;   // 0..2303
            float bv = bias[cc];
            int sec = cc / DD;                    // 0=q 1=k 2=v (uniform per 16-group)
            int within = cc - sec * DD;
            int hh = within / DHH;                // uniform per 16-group (96 = 6*16)
            int dd = within - hh * DHH;
#pragma unroll
            for (int reg = 0; reg < 4; ++reg) {
                int rr = m0 + wr * 64 + i * 16 + q * 4 + reg;  // token
                float v = acc[i][j][reg] + bv;
                int b = rr >> 9, s = rr & 511;
                int bh = b * HH + hh;
                if (sec == 0)
                    Qh[((size_t)bh * SS + s) * 128 + dd] = __float2bfloat16(v * scale);
                else if (sec == 1)
                    Kh[((size_t)bh * SS + s) * 128 + dd] = __float2bfloat16(v);
                else
                    Vt[((size_t)bh * 128 + dd) * SS + s] = __float2bfloat16(v);
            }
        }
    }
}

// ---------------------------------------------------------------------------
// Batched score GEMM: Sc[bh] = Qh[bh] @ Kh[bh]^T   (scale folded into Q)
// M=N=512, K=128 (zero-padded head dim). Skips upper-triangle tiles.
// ---------------------------------------------------------------------------
__global__ __launch_bounds__(256, 5) void gemm_sc(
    const bf16_t* __restrict__ Qh, const bf16_t* __restrict__ Kh,
    bf16_t* __restrict__ Scb) {
    const int bh = blockIdx.z;
    const int m0 = blockIdx.y * 128;
    const int n0 = blockIdx.x * 128;
    if (n0 > m0) return;  // fully above the causal diagonal
    const bf16_t* A = Qh + (size_t)bh * SS * 128;
    const bf16_t* W = Kh + (size_t)bh * SS * 128;
    __shared__ uint4 As4[128 * 8];
    __shared__ uint4 Bs4[128 * 8];
    const int lane = threadIdx.x & 63, wave = threadIdx.x >> 6;
    const int wr = wave >> 1, wc = wave & 1;
    const int r = lane & 15, q = lane >> 4;
    const int K = 128;

    f32x4 acc[4][4];
#pragma unroll
    for (int i = 0; i < 4; ++i)
#pragma unroll
        for (int j = 0; j < 4; ++j) acc[i][j] = f32x4{0.f, 0.f, 0.f, 0.f};

    for (int k0 = 0; k0 < K; k0 += 64) {
#pragma unroll
        for (int it = 0; it < 4; ++it) {
            int base = it * 256 + wave * 64;
            int c = base + lane;
            int row = c >> 3, pc = c & 7;
            int kc = pc ^ (row & 7);
            load_lds16(A + (size_t)(m0 + row) * K + k0 + kc * 8, &As4[base]);
            load_lds16(W + (size_t)(n0 + row) * K + k0 + kc * 8, &Bs4[base]);
        }
        __syncthreads();
#pragma unroll
        for (int kk = 0; kk < 2; ++kk) {
            bf16x8 af[4], bfr[4];
            int lc = kk * 4 + q;
#pragma unroll
            for (int i = 0; i < 4; ++i) {
                int rowA = wr * 64 + i * 16 + r;
                af[i] = *reinterpret_cast<const bf16x8*>(&As4[rowA * 8 + (lc ^ (rowA & 7))]);
                int rowB = wc * 64 + i * 16 + r;
                bfr[i] = *reinterpret_cast<const bf16x8*>(&Bs4[rowB * 8 + (lc ^ (rowB & 7))]);
            }
#pragma unroll
            for (int i = 0; i < 4; ++i)
#pragma unroll
                for (int j = 0; j < 4; ++j)
                    acc[i][j] = __builtin_amdgcn_mfma_f32_16x16x32_bf16(af[i], bfr[j], acc[i][j], 0, 0, 0);
        }
        __syncthreads();
    }

    bf16_t* out = Scb + (size_t)bh * SS * SS;
#pragma unroll
    for (int i = 0; i < 4; ++i) {
#pragma unroll
        for (int j = 0; j < 4; ++j) {
            int cc = n0 + wc * 64 + j * 16 + r;
#pragma unroll
            for (int reg = 0; reg < 4; ++reg) {
                int rr = m0 + wr * 64 + i * 16 + q * 4 + reg;
                out[(size_t)rr * SS + cc] = __float2bfloat16(acc[i][j][reg]);
            }
        }
    }
}

// ---------------------------------------------------------------------------
// Causal softmax in place over bf16 scores. One wave per row of 512.
// ---------------------------------------------------------------------------
__global__ __launch_bounds__(256) void softmax_kernel(bf16_t* __restrict__ Scb) {
    const int wave = threadIdx.x >> 6, lane = threadIdx.x & 63;
    const int row = blockIdx.x * 4 + wave;   // bh*512 + q
    const int qpos = row & (SS - 1);
    const int kn = qpos + 1;
    bf16_t* rp = Scb + (size_t)row * SS;
    union {
        uint4 v;
        bf16_t h[8];
    } u;
    u.v = *reinterpret_cast<const uint4*>(rp + lane * 8);
    float vals[8];
    float m = -1e30f;
#pragma unroll
    for (int e = 0; e < 8; ++e) {
        int j = lane * 8 + e;
        vals[e] = (j < kn) ? __bfloat162float(u.h[e]) : -1e30f;
        m = fmaxf(m, vals[e]);
    }
#pragma unroll
    for (int s = 1; s < 64; s <<= 1) m = fmaxf(m, __shfl_xor(m, s));
    float sum = 0.f;
#pragma unroll
    for (int e = 0; e < 8; ++e) {
        vals[e] = __expf(vals[e] - m);
        sum += vals[e];
    }
#pragma unroll
    for (int s = 1; s < 64; s <<= 1) sum += __shfl_xor(sum, s);
    const float inv = 1.f / sum;
#pragma unroll
    for (int e = 0; e < 8; ++e) u.h[e] = __float2bfloat16(vals[e] * inv);
    *reinterpret_cast<uint4*>(rp + lane * 8) = u.v;
}

// ---------------------------------------------------------------------------
// Batched P@V GEMM: ao[bh rows] = P[bh] (512x512 bf16) @ Vt[bh]^T (128x512)
// N tile = 128 (cols 96..127 garbage, guarded). Writes ao [T,768] bf16.
// ---------------------------------------------------------------------------
__global__ __launch_bounds__(256, 5) void gemm_pv(
    const bf16_t* __restrict__ P, const bf16_t* __restrict__ Vt,
    bf16_t* __restrict__ ao) {
    const int bh = blockIdx.z;
    const int m0 = blockIdx.y * 128;
    const bf16_t* A = P + (size_t)bh * SS * SS;
    const bf16_t* W = Vt + (size_t)bh * 128 * SS;
    __shared__ uint4 As4[128 * 8];
    __shared__ uint4 Bs4[128 * 8];
    const int lane = threadIdx.x & 63, wave = threadIdx.x >> 6;
    const int wr = wave >> 1, wc = wave & 1;
    const int r = lane & 15, q = lane >> 4;
    const int K = SS;  // 512

    f32x4 acc[4][4];
#pragma unroll
    for (int i = 0; i < 4; ++i)
#pragma unroll
        for (int j = 0; j < 4; ++j) acc[i][j] = f32x4{0.f, 0.f, 0.f, 0.f};

    for (int k0 = 0; k0 < K; k0 += 64) {
#pragma unroll
        for (int it = 0; it < 4; ++it) {
            int base = it * 256 + wave * 64;
            int c = base + lane;
            int row = c >> 3, pc = c & 7;
            int kc = pc ^ (row & 7);
            load_lds16(A + (size_t)(m0 + row) * K + k0 + kc * 8, &As4[base]);
            load_lds16(W + (size_t)row * K + k0 + kc * 8, &Bs4[base]);
        }
        __syncthreads();
#pragma unroll
        for (int kk = 0; kk < 2; ++kk) {
            bf16x8 af[4], bfr[4];
            int lc = kk * 4 + q;
#pragma unroll
            for (int i = 0; i < 4; ++i) {
                int rowA = wr * 64 + i * 16 + r;
                af[i] = *reinterpret_cast<const bf16x8*>(&As4[rowA * 8 + (lc ^ (rowA & 7))]);
                int rowB = wc * 64 + i * 16 + r;
                bfr[i] = *reinterpret_cast<const bf16x8*>(&Bs4[rowB * 8 + (lc ^ (rowB & 7))]);
            }
#pragma unroll
            for (int i = 0; i < 4; ++i)
#pragma unroll
                for (int j = 0; j < 4; ++j)
                    acc[i][j] = __builtin_amdgcn_mfma_f32_16x16x32_bf16(af[i], bfr[j], acc[i][j], 0, 0, 0);
        }
        __syncthreads();
    }

    const int b = bh >> 3, hh = bh & 7;
#pragma unroll
    for (int i = 0; i < 4; ++i) {
#pragma unroll
        for (int j = 0; j < 4; ++j) {
            int cc = wc * 64 + j * 16 + r;  // head dim 0..127
            if (cc < DHH) {
#pragma unroll
                for (int reg = 0; reg < 4; ++reg) {
                    int s = m0 + wr * 64 + i * 16 + q * 4 + reg;
                    size_t t = (size_t)b * SS + s;
                    ao[t * DD + hh * DHH + cc] = __float2bfloat16(acc[i][j][reg]);
                }
            }
        }
    }
}

// ---------------------------------------------------------------------------
// LayerNorm over D=768. In-place safe.
// ---------------------------------------------------------------------------
__global__ __launch_bounds__(256) void ln_kernel(const float* __restrict__ in,
                                                 const float* __restrict__ g,
                                                 const float* __restrict__ beta,
                                                 float* __restrict__ xo,
                                                 bf16_t* __restrict__ xb) {
    const int row = blockIdx.x;
    const int tid = threadIdx.x;
    const float* ip = in + (size_t)row * DD;
    float v[3];
#pragma unroll
    for (int t = 0; t < 3; ++t) v[t] = ip[tid + t * 256];
    float s = v[0] + v[1] + v[2];
    float ss = v[0] * v[0] + v[1] * v[1] + v[2] * v[2];
    for (int off = 32; off > 0; off >>= 1) {
        s += __shfl_down(s, off);
        ss += __shfl_down(ss, off);
    }
    __shared__ float red[8];
    if ((tid & 63) == 0) {
        red[(tid >> 6) * 2] = s;
        red[(tid >> 6) * 2 + 1] = ss;
    }
    __syncthreads();
    s = red[0] + red[2] + red[4] + red[6];
    ss = red[1] + red[3] + red[5] + red[7];
    const float mean = s * (1.f / DD);
    const float var = ss * (1.f / DD) - mean * mean;
    const float rs = rsqrtf(var + 1e-5f);
#pragma unroll
    for (int t = 0; t < 3; ++t) {
        int d = tid + t * 256;
        float y = (v[t] - mean) * rs * g[d] + beta[d];
        xo[(size_t)row * DD + d] = y;
        xb[(size_t)row * DD + d] = __float2bfloat16(y);
    }
}

// ---------------------------------------------------------------------------
// Fused LN1 -> +cv broadcast -> LN2. Reads tmp once, writes x + xb once.
// ---------------------------------------------------------------------------
__global__ __launch_bounds__(256) void ln12_kernel(const float* __restrict__ in,
                                                   const float* __restrict__ cvv,
                                                   const float* __restrict__ g1,
                                                   const float* __restrict__ b1,
                                                   const float* __restrict__ g2,
                                                   const float* __restrict__ b2,
                                                   float* __restrict__ xo,
                                                   bf16_t* __restrict__ xb) {
    const int row = blockIdx.x;
    const int tid = threadIdx.x;
    const float* ip = in + (size_t)row * DD;
    const float* cp = cvv + (size_t)(row >> 9) * DD;
    __shared__ float red[8];
    float v[3];
#pragma unroll
    for (int t = 0; t < 3; ++t) v[t] = ip[tid + t * 256];
    // ---- LN1
    float s = v[0] + v[1] + v[2];
    float ss = v[0] * v[0] + v[1] * v[1] + v[2] * v[2];
    for (int off = 32; off > 0; off >>= 1) {
        s += __shfl_down(s, off);
        ss += __shfl_down(ss, off);
    }
    if ((tid & 63) == 0) {
        red[(tid >> 6) * 2] = s;
        red[(tid >> 6) * 2 + 1] = ss;
    }
    __syncthreads();
    s = red[0] + red[2] + red[4] + red[6];
    ss = red[1] + red[3] + red[5] + red[7];
    float mean = s * (1.f / DD);
    float var = ss * (1.f / DD) - mean * mean;
    float rs = rsqrtf(var + 1e-5f);
#pragma unroll
    for (int t = 0; t < 3; ++t) {
        int d = tid + t * 256;
        v[t] = (v[t] - mean) * rs * g1[d] + b1[d] + cp[d];
    }
    // ---- LN2
    s = v[0] + v[1] + v[2];
    ss = v[0] * v[0] + v[1] * v[1] + v[2] * v[2];
    for (int off = 32; off > 0; off >>= 1) {
        s += __shfl_down(s, off);
        ss += __shfl_down(ss, off);
    }
    __syncthreads();  // protect red reuse
    if ((tid & 63) == 0) {
        red[(tid >> 6) * 2] = s;
        red[(tid >> 6) * 2 + 1] = ss;
    }
    __syncthreads();
    s = red[0] + red[2] + red[4] + red[6];
    ss = red[1] + red[3] + red[5] + red[7];
    mean = s * (1.f / DD);
    var = ss * (1.f / DD) - mean * mean;
    rs = rsqrtf(var + 1e-5f);
#pragma unroll
    for (int t = 0; t < 3; ++t) {
        int d = tid + t * 256;
        float y = (v[t] - mean) * rs * g2[d] + b2[d];
        xo[(size_t)row * DD + d] = y;
        xb[(size_t)row * DD + d] = __float2bfloat16(y);
    }
}

// ---------------------------------------------------------------------------
// Host launcher
// ---------------------------------------------------------------------------
extern "C" void kernel_launch(void* const* d_in, const int* in_sizes, int n_in,
                              void* d_out, int out_size, void* d_ws, size_t ws_size,
                              hipStream_t stream) {
    (void)in_sizes; (void)n_in; (void)out_size; (void)ws_size;
    const float* latent   = (const float*)d_in[0];
    const int*   target   = (const int*)d_in[1];
    const float* tok_emb  = (const float*)d_in[2];
    const float* pos_emb  = (const float*)d_in[3];
    const float* sa_w_qkv = (const float*)d_in[4];
    const float* sa_b_qkv = (const float*)d_in[5];
    const float* sa_w_o   = (const float*)d_in[6];
    const float* sa_b_o   = (const float*)d_in[7];
    const float* ca_w_qkv = (const float*)d_in[8];
    const float* ca_b_qkv = (const float*)d_in[9];
    const float* ca_w_o   = (const float*)d_in[10];
    const float* ca_b_o   = (const float*)d_in[11];
    const float* ffn_w1   = (const float*)d_in[12];
    const float* ffn_b1   = (const float*)d_in[13];
    const float* ffn_w2   = (const float*)d_in[14];
    const float* ffn_b2   = (const float*)d_in[15];
    const float* ln1_g    = (const float*)d_in[16];
    const float* ln1_b    = (const float*)d_in[17];
    const float* ln2_g    = (const float*)d_in[18];
    const float* ln2_b    = (const float*)d_in[19];
    const float* ln3_g    = (const float*)d_in[20];
    const float* ln3_b    = (const float*)d_in[21];
    const float* out_w    = (const float*)d_in[22];
    const float* out_b    = (const float*)d_in[23];
    float* out = (float*)d_out;

    // workspace carve-up (256B aligned)
    char* ws = (char*)d_ws;
    size_t off = 0;
    auto alloc = [&](size_t bytes) {
        void* p = ws + off;
        off += (bytes + 255) & ~(size_t)255;
        return p;
    };
    float*  x    = (float*)alloc((size_t)TT * DD * 4);        // residual stream fp32
    bf16_t* xb   = (bf16_t*)alloc((size_t)TT * DD * 2);       // bf16 shadow
    bf16_t* ao   = (bf16_t*)alloc((size_t)TT * DD * 2);       // attn out bf16
    float*  cv   = (float*)alloc((size_t)LL * BB * DD * 4);   // cross-attn vectors
    float*  v16  = (float*)alloc((size_t)LL * BB * DD * 4);   // cv stage-1 temp
    bf16_t* wqkv_b = (bf16_t*)alloc((size_t)LL * 3 * DD * DD * 2);
    bf16_t* wo_b   = (bf16_t*)alloc((size_t)LL * DD * DD * 2);
    bf16_t* w1_b   = (bf16_t*)alloc((size_t)LL * FF * DD * 2);
    bf16_t* w2_b   = (bf16_t*)alloc((size_t)LL * DD * FF * 2);
    bf16_t* wout_b = (bf16_t*)alloc((size_t)128 * DD * 2);
    // Attention region:
    //   Qh [128][512][128] bf16 (16.78 MB)  zero-padded cols 96..127 (filled once)
    //   Kh [128][512][128] bf16 (16.78 MB)  zero-padded cols 96..127 (filled once)
    //   Vt [128][128][512] bf16 (16.78 MB)  rows 96..127 unused garbage (guarded)
    //   Scb[128][512][512] bf16 (67.1 MB)   scores, then P in place
    char* attnR = (char*)alloc((size_t)BH * SS * 128 * 2 * 3 + (size_t)BH * SS * SS * 2);
    bf16_t* Qh  = (bf16_t*)attnR;
    bf16_t* Kh  = Qh + (size_t)BH * SS * 128;
    bf16_t* Vt  = Kh + (size_t)BH * SS * 128;
    bf16_t* Scb = Vt + (size_t)BH * 128 * SS;
    // FFN-phase overlays go inside Scb ONLY (67.1 MB >= 33.6 + 25.2 MB).
    // Qh/Kh must never be overwritten: their zero pad columns are filled once
    // and reused across all layers. Stale upper-triangle data in Scb is
    // masked by the causal softmax.
    bf16_t* h   = Scb;                                         // [T,2048] bf16 (33.6 MB)
    float*  tmp = (float*)((char*)Scb + ((size_t)34 << 20));   // [T,768] fp32 (25.2 MB)

    // weight conversions (every call: ws is re-poisoned)
    cvt_kernel<<<2048, 256, 0, stream>>>(sa_w_qkv, wqkv_b, LL * 3 * DD * DD);
    cvt_kernel<<<2048, 256, 0, stream>>>(sa_w_o, wo_b, LL * DD * DD);
    cvt_kernel<<<2048, 256, 0, stream>>>(ffn_w1, w1_b, LL * FF * DD);
    cvt_kernel<<<2048, 256, 0, stream>>>(ffn_w2, w2_b, LL * DD * FF);
    pad_wout_kernel<<<(128 * DD) / 256, 256, 0, stream>>>(out_w, wout_b);
    // zero Qh+Kh (pad columns 96..127 must be 0; zero both fully, once per call)
    {
        int n4 = (int)(((size_t)BH * SS * 128 * 2 * 2) / 16);  // uint4 count
        fill_zero_kernel<<<(n4 + 255) / 256, 256, 0, stream>>>((uint4*)Qh, n4);
    }

    // collapsed cross-attention: v16 = latent @ Wv^T + bv; cv = v16 @ Wo^T + bo
    cvmm_kernel<<<dim3(DD / 16, LL), 256, 0, stream>>>(
        latent, 0, ca_w_qkv, (size_t)3 * DD * DD, (size_t)2 * DD * DD,
        ca_b_qkv, (size_t)3 * DD, (size_t)2 * DD, v16);
    cvmm_kernel<<<dim3(DD / 16, LL), 256, 0, stream>>>(
        v16, BB * DD, ca_w_o, (size_t)DD * DD, 0,
        ca_b_o, (size_t)DD, 0, cv);

    // embeddings
    embed_kernel<<<TT, 256, 0, stream>>>(target, tok_emb, pos_emb, x, xb);

    for (int i = 0; i < LL; ++i) {
        // QKV projection -> Qh/Kh/Vt (head-major bf16, scale folded into Q)
        gemm_qkv<<<dim3(3 * DD / 128, TT / 128), 256, 0, stream>>>(
            xb, wqkv_b + (size_t)i * 3 * DD * DD, sa_b_qkv + (size_t)i * 3 * DD,
            Qh, Kh, Vt);
        // scores (lower-triangle tiles only)
        gemm_sc<<<dim3(4, 4, BH), 256, 0, stream>>>(Qh, Kh, Scb);
        // causal softmax in place -> P (bf16, zeros above diagonal)
        softmax_kernel<<<(BH * SS) / 4, 256, 0, stream>>>(Scb);
        // P @ V -> ao
        gemm_pv<<<dim3(1, 4, BH), 256, 0, stream>>>(Scb, Vt, ao);
        // O projection + residual -> tmp
        gemm_bt<false, false, true><<<dim3(DD / 128, TT / 128), 256, 0, stream>>>(
            ao, wo_b + (size_t)i * DD * DD, sa_b_o + (size_t)i * DD,
            x, tmp, nullptr, DD, DD, DD);
        // LN1 + cv + LN2 fused -> x, xb
        ln12_kernel<<<TT, 256, 0, stream>>>(tmp, cv + (size_t)i * BB * DD,
                                            ln1_g + (size_t)i * DD, ln1_b + (size_t)i * DD,
                                            ln2_g + (size_t)i * DD, ln2_b + (size_t)i * DD,
                                            x, xb);
        // FFN1: relu(x@W1^T+b1) -> h (bf16)
        gemm_bt<true, true, false><<<dim3(FF / 128, TT / 128), 256, 0, stream>>>(
            xb, w1_b + (size_t)i * FF * DD, ffn_b1 + (size_t)i * FF,
            nullptr, nullptr, h, DD, FF, FF);
        // FFN2 + residual -> tmp
        gemm_bt<false, false, true><<<dim3(DD / 128, TT / 128), 256, 0, stream>>>(
            h, w2_b + (size_t)i * DD * FF, ffn_b2 + (size_t)i * DD,
            x, tmp, nullptr, FF, DD, DD);
        // LN3 -> x, xb
        ln_kernel<<<TT, 256, 0, stream>>>(tmp, ln3_g + (size_t)i * DD,
                                          ln3_b + (size_t)i * DD, x, xb);
    }

    // final projection to logits [8192,100] (padded N=128, guarded)
    gemm_bt<false, false, false><<<dim3(1, TT / 128), 256, 0, stream>>>(
        xb, wout_b, out_b, nullptr, out, nullptr, DD, VV, VV);
}

// Round 6
// 1868.738 us; speedup vs baseline: 1.6527x; 1.6527x over previous
//
#include <hip/hip_runtime.h>
#include <hip/hip_bf16.h>

// Problem constants
#define BB 16
#define SS 512
#define DD 768
#define HH 8
#define VV 100
#define FF 2048
#define LL 6
#define DHH 96
#define TT (BB * SS)  // 8192 token rows
#define BH (BB * HH)  // 128 (batch,head) pairs

typedef __bf16 bf16x8 __attribute__((ext_vector_type(8)));
typedef float f32x4 __attribute__((ext_vector_type(4)));
typedef __hip_bfloat16 bf16_t;

// async global->LDS, 16B per lane; deposit = wave-uniform lds base + lane*16
__device__ __forceinline__ void load_lds16(const void* g, void* l) {
    __builtin_amdgcn_global_load_lds(
        (const __attribute__((address_space(1))) void*)g,
        (__attribute__((address_space(3))) void*)l, 16, 0, 0);
}

// ---------------------------------------------------------------------------
// fp32 -> bf16 conversion (grid-stride)
// ---------------------------------------------------------------------------
__global__ void cvt_kernel(const float* __restrict__ s, bf16_t* __restrict__ d, int n) {
    int i = blockIdx.x * blockDim.x + threadIdx.x;
    int stride = gridDim.x * blockDim.x;
    for (; i < n; i += stride) d[i] = __float2bfloat16(s[i]);
}

__global__ void fill_zero_kernel(uint4* __restrict__ p, int n) {
    int i = blockIdx.x * blockDim.x + threadIdx.x;
    if (i < n) p[i] = uint4{0u, 0u, 0u, 0u};
}

// out_w [100,768] -> padded bf16 [128,768] (rows 100..127 zero)
__global__ void pad_wout_kernel(const float* __restrict__ s, bf16_t* __restrict__ d) {
    int i = blockIdx.x * blockDim.x + threadIdx.x;  // exactly 128*768 threads
    int row = i / DD;
    d[i] = (row < VV) ? __float2bfloat16(s[i]) : __float2bfloat16(0.f);
}

// ---------------------------------------------------------------------------
// Embedding: x[t,:] = tok_emb[target[t],:] + pos_emb[s,:]  (writes fp32 + bf16)
// ---------------------------------------------------------------------------
__global__ void embed_kernel(const int* __restrict__ target,
                             const float* __restrict__ tok_emb,
                             const float* __restrict__ pos_emb,
                             float* __restrict__ x, bf16_t* __restrict__ xb) {
    int t = blockIdx.x;            // 0..8191
    int s = t & (SS - 1);
    int tok = target[t];
    const float* te = tok_emb + (size_t)tok * DD;
    const float* pe = pos_emb + (size_t)s * DD;
    for (int d = threadIdx.x; d < DD; d += blockDim.x) {
        float v = te[d] + pe[d];
        x[(size_t)t * DD + d] = v;
        xb[(size_t)t * DD + d] = __float2bfloat16(v);
    }
}

// ---------------------------------------------------------------------------
// Collapsed cross-attention, batched over all 16 latents per weight read.
// ---------------------------------------------------------------------------
__global__ __launch_bounds__(256) void cvmm_kernel(
    const float* __restrict__ in, int in_per_layer,
    const float* __restrict__ Wbase, size_t w_stride, size_t w_off,
    const float* __restrict__ bbase, size_t b_stride, size_t b_off,
    float* __restrict__ outp) {
    const int jc = blockIdx.x;
    const int layer = blockIdx.y;
    __shared__ float inb[BB][DD + 4];
    const int tid = threadIdx.x;
    const float* ip = in + (size_t)layer * in_per_layer;
    for (int idx = tid; idx < BB * DD; idx += 256) {
        int b = idx / DD, d = idx - b * DD;
        inb[b][d] = ip[(size_t)b * DD + d];
    }
    __syncthreads();
    const int j = jc * 16 + (tid >> 4);
    const int b = tid & 15;
    const float4* w4 = reinterpret_cast<const float4*>(
        Wbase + (size_t)layer * w_stride + w_off + (size_t)j * DD);
    const float4* i4 = reinterpret_cast<const float4*>(&inb[b][0]);
    float a = 0.f;
#pragma unroll 4
    for (int d = 0; d < DD / 4; ++d) {
        float4 w = w4[d], xv = i4[d];
        a += w.x * xv.x + w.y * xv.y + w.z * xv.z + w.w * xv.w;
    }
    a += bbase[(size_t)layer * b_stride + b_off + j];
    outp[((size_t)layer * BB + b) * DD + j] = a;
}

// ---------------------------------------------------------------------------
// bf16 MFMA GEMM: C[M,N] = A[M,K] @ W[N,K]^T + bias (+resid) (+relu)
// 128x128 tile, BK=64, 256 threads = 4 waves, each wave 64x64 (4x4 mfma tiles).
// Staging via global_load_lds width=16 (m97), XOR swizzle on the global side.
// __launch_bounds__(256,3): R5 measured that forcing 5 blocks/CU makes the
// compiler squeeze VGPR 60->48 (spill traffic: WRITE_SIZE doubled) and
// thrashes L2 (FETCH +40%) -> MfmaUtil halved. 3 is the proven operating point.
// ---------------------------------------------------------------------------
template <bool RELU, bool BOUT, bool RES>
__global__ __launch_bounds__(256, 3) void gemm_bt(
    const bf16_t* __restrict__ A, const bf16_t* __restrict__ W,
    const float* __restrict__ bias, const float* __restrict__ resid,
    float* __restrict__ Cf, bf16_t* __restrict__ Cb,
    int K, int ldc, int Nreal) {
    __shared__ uint4 As4[128 * 8];
    __shared__ uint4 Bs4[128 * 8];
    const int m0 = blockIdx.y * 128;
    const int n0 = blockIdx.x * 128;
    const int lane = threadIdx.x & 63, wave = threadIdx.x >> 6;
    const int wr = wave >> 1, wc = wave & 1;
    const int r = lane & 15, q = lane >> 4;

    f32x4 acc[4][4];
#pragma unroll
    for (int i = 0; i < 4; ++i)
#pragma unroll
        for (int j = 0; j < 4; ++j) acc[i][j] = f32x4{0.f, 0.f, 0.f, 0.f};

    for (int k0 = 0; k0 < K; k0 += 64) {
#pragma unroll
        for (int it = 0; it < 4; ++it) {
            int base = it * 256 + wave * 64;  // wave-uniform LDS chunk base
            int c = base + lane;
            int row = c >> 3, pc = c & 7;
            int kc = pc ^ (row & 7);
            load_lds16(A + (size_t)(m0 + row) * K + k0 + kc * 8, &As4[base]);
            load_lds16(W + (size_t)(n0 + row) * K + k0 + kc * 8, &Bs4[base]);
        }
        __syncthreads();
#pragma unroll
        for (int kk = 0; kk < 2; ++kk) {
            bf16x8 af[4], bfr[4];
            int lc = kk * 4 + q;
#pragma unroll
            for (int i = 0; i < 4; ++i) {
                int rowA = wr * 64 + i * 16 + r;
                af[i] = *reinterpret_cast<const bf16x8*>(&As4[rowA * 8 + (lc ^ (rowA & 7))]);
                int rowB = wc * 64 + i * 16 + r;
                bfr[i] = *reinterpret_cast<const bf16x8*>(&Bs4[rowB * 8 + (lc ^ (rowB & 7))]);
            }
#pragma unroll
            for (int i = 0; i < 4; ++i)
#pragma unroll
                for (int j = 0; j < 4; ++j)
                    acc[i][j] = __builtin_amdgcn_mfma_f32_16x16x32_bf16(af[i], bfr[j], acc[i][j], 0, 0, 0);
        }
        __syncthreads();
    }

#pragma unroll
    for (int i = 0; i < 4; ++i) {
#pragma unroll
        for (int j = 0; j < 4; ++j) {
            int cc = n0 + wc * 64 + j * 16 + r;
            if (cc < Nreal) {
                float bv = bias[cc];
#pragma unroll
                for (int reg = 0; reg < 4; ++reg) {
                    int rr = m0 + wr * 64 + i * 16 + q * 4 + reg;
                    float v = acc[i][j][reg] + bv;
                    if (RES) v += resid[(size_t)rr * ldc + cc];
                    if (RELU) v = fmaxf(v, 0.f);
                    if (BOUT) Cb[(size_t)rr * ldc + cc] = __float2bfloat16(v);
                    else Cf[(size_t)rr * ldc + cc] = v;
                }
            }
        }
    }
}

// ---------------------------------------------------------------------------
// QKV projection GEMM with head-scatter epilogue.
// Writes: Qh [bh][512][128] bf16 (scaled by 1/sqrt(96), cols 96..127 pre-zeroed)
//         Kh [bh][512][128] bf16
//         Vt [bh][128][512] bf16 (transposed; rows 96..127 unused garbage)
// ---------------------------------------------------------------------------
__global__ __launch_bounds__(256, 3) void gemm_qkv(
    const bf16_t* __restrict__ A, const bf16_t* __restrict__ W,
    const float* __restrict__ bias,
    bf16_t* __restrict__ Qh, bf16_t* __restrict__ Kh, bf16_t* __restrict__ Vt) {
    __shared__ uint4 As4[128 * 8];
    __shared__ uint4 Bs4[128 * 8];
    const int m0 = blockIdx.y * 128;
    const int n0 = blockIdx.x * 128;
    const int lane = threadIdx.x & 63, wave = threadIdx.x >> 6;
    const int wr = wave >> 1, wc = wave & 1;
    const int r = lane & 15, q = lane >> 4;
    const int K = DD;

    f32x4 acc[4][4];
#pragma unroll
    for (int i = 0; i < 4; ++i)
#pragma unroll
        for (int j = 0; j < 4; ++j) acc[i][j] = f32x4{0.f, 0.f, 0.f, 0.f};

    for (int k0 = 0; k0 < K; k0 += 64) {
#pragma unroll
        for (int it = 0; it < 4; ++it) {
            int base = it * 256 + wave * 64;
            int c = base + lane;
            int row = c >> 3, pc = c & 7;
            int kc = pc ^ (row & 7);
            load_lds16(A + (size_t)(m0 + row) * K + k0 + kc * 8, &As4[base]);
            load_lds16(W + (size_t)(n0 + row) * K + k0 + kc * 8, &Bs4[base]);
        }
        __syncthreads();
#pragma unroll
        for (int kk = 0; kk < 2; ++kk) {
            bf16x8 af[4], bfr[4];
            int lc = kk * 4 + q;
#pragma unroll
            for (int i = 0; i < 4; ++i) {
                int rowA = wr * 64 + i * 16 + r;
                af[i] = *reinterpret_cast<const bf16x8*>(&As4[rowA * 8 + (lc ^ (rowA & 7))]);
                int rowB = wc * 64 + i * 16 + r;
                bfr[i] = *reinterpret_cast<const bf16x8*>(&Bs4[rowB * 8 + (lc ^ (rowB & 7))]);
            }
#pragma unroll
            for (int i = 0; i < 4; ++i)
#pragma unroll
                for (int j = 0; j < 4; ++j)
                    acc[i][j] = __builtin_amdgcn_mfma_f32_16x16x32_bf16(af[i], bfr[j], acc[i][j], 0, 0, 0);
        }
        __syncthreads();
    }

    const float scale = 0.10206207261596575f;  // 1/sqrt(96)
#pragma unroll
    for (int i = 0; i < 4; ++i) {
#pragma unroll
        for (int j = 0; j < 4; ++j) {
            int cc = n0 + wc * 64 + j * 16 + r;   // 0..2303
            float bv = bias[cc];
            int sec = cc / DD;                    // 0=q 1=k 2=v (uniform per 16-group)
            int within = cc - sec * DD;
            int hh = within / DHH;                // uniform per 16-group (96 = 6*16)
            int dd = within - hh * DHH;
#pragma unroll
            for (int reg = 0; reg < 4; ++reg) {
                int rr = m0 + wr * 64 + i * 16 + q * 4 + reg;  // token
                float v = acc[i][j][reg] + bv;
                int b = rr >> 9, s = rr & 511;
                int bh = b * HH + hh;
                if (sec == 0)
                    Qh[((size_t)bh * SS + s) * 128 + dd] = __float2bfloat16(v * scale);
                else if (sec == 1)
                    Kh[((size_t)bh * SS + s) * 128 + dd] = __float2bfloat16(v);
                else
                    Vt[((size_t)bh * 128 + dd) * SS + s] = __float2bfloat16(v);
            }
        }
    }
}

// ---------------------------------------------------------------------------
// Batched score GEMM: Sc[bh] = Qh[bh] @ Kh[bh]^T   (scale folded into Q)
// M=N=512, K=128 (zero-padded head dim). Skips upper-triangle tiles.
// ---------------------------------------------------------------------------
__global__ __launch_bounds__(256, 3) void gemm_sc(
    const bf16_t* __restrict__ Qh, const bf16_t* __restrict__ Kh,
    bf16_t* __restrict__ Scb) {
    const int bh = blockIdx.z;
    const int m0 = blockIdx.y * 128;
    const int n0 = blockIdx.x * 128;
    if (n0 > m0) return;  // fully above the causal diagonal
    const bf16_t* A = Qh + (size_t)bh * SS * 128;
    const bf16_t* W = Kh + (size_t)bh * SS * 128;
    __shared__ uint4 As4[128 * 8];
    __shared__ uint4 Bs4[128 * 8];
    const int lane = threadIdx.x & 63, wave = threadIdx.x >> 6;
    const int wr = wave >> 1, wc = wave & 1;
    const int r = lane & 15, q = lane >> 4;
    const int K = 128;

    f32x4 acc[4][4];
#pragma unroll
    for (int i = 0; i < 4; ++i)
#pragma unroll
        for (int j = 0; j < 4; ++j) acc[i][j] = f32x4{0.f, 0.f, 0.f, 0.f};

    for (int k0 = 0; k0 < K; k0 += 64) {
#pragma unroll
        for (int it = 0; it < 4; ++it) {
            int base = it * 256 + wave * 64;
            int c = base + lane;
            int row = c >> 3, pc = c & 7;
            int kc = pc ^ (row & 7);
            load_lds16(A + (size_t)(m0 + row) * K + k0 + kc * 8, &As4[base]);
            load_lds16(W + (size_t)(n0 + row) * K + k0 + kc * 8, &Bs4[base]);
        }
        __syncthreads();
#pragma unroll
        for (int kk = 0; kk < 2; ++kk) {
            bf16x8 af[4], bfr[4];
            int lc = kk * 4 + q;
#pragma unroll
            for (int i = 0; i < 4; ++i) {
                int rowA = wr * 64 + i * 16 + r;
                af[i] = *reinterpret_cast<const bf16x8*>(&As4[rowA * 8 + (lc ^ (rowA & 7))]);
                int rowB = wc * 64 + i * 16 + r;
                bfr[i] = *reinterpret_cast<const bf16x8*>(&Bs4[rowB * 8 + (lc ^ (rowB & 7))]);
            }
#pragma unroll
            for (int i = 0; i < 4; ++i)
#pragma unroll
                for (int j = 0; j < 4; ++j)
                    acc[i][j] = __builtin_amdgcn_mfma_f32_16x16x32_bf16(af[i], bfr[j], acc[i][j], 0, 0, 0);
        }
        __syncthreads();
    }

    bf16_t* out = Scb + (size_t)bh * SS * SS;
#pragma unroll
    for (int i = 0; i < 4; ++i) {
#pragma unroll
        for (int j = 0; j < 4; ++j) {
            int cc = n0 + wc * 64 + j * 16 + r;
#pragma unroll
            for (int reg = 0; reg < 4; ++reg) {
                int rr = m0 + wr * 64 + i * 16 + q * 4 + reg;
                out[(size_t)rr * SS + cc] = __float2bfloat16(acc[i][j][reg]);
            }
        }
    }
}

// ---------------------------------------------------------------------------
// Causal softmax in place over bf16 scores. One wave per row of 512.
// Only [0, kend) is processed, where kend = end of this row's q-tile:
// gemm_pv never reads kv >= kend (its K-loop stops at m0+128 == kend for
// every row in the tile). Zeros are still written for [kn, kend).
// ---------------------------------------------------------------------------
__global__ __launch_bounds__(256) void softmax_kernel(bf16_t* __restrict__ Scb) {
    const int wave = threadIdx.x >> 6, lane = threadIdx.x & 63;
    const int row = blockIdx.x * 4 + wave;   // bh*512 + q
    const int qpos = row & (SS - 1);
    const int kn = qpos + 1;
    const int kend = ((qpos >> 7) + 1) << 7;  // 128/256/384/512 (wave-uniform)
    const bool act = (lane << 3) < kend;
    bf16_t* rp = Scb + (size_t)row * SS;
    union {
        uint4 v;
        bf16_t h[8];
    } u;
    float vals[8];
    float m = -1e30f;
    if (act) {
        u.v = *reinterpret_cast<const uint4*>(rp + lane * 8);
#pragma unroll
        for (int e = 0; e < 8; ++e) {
            int j = lane * 8 + e;
            vals[e] = (j < kn) ? __bfloat162float(u.h[e]) : -1e30f;
            m = fmaxf(m, vals[e]);
        }
    } else {
#pragma unroll
        for (int e = 0; e < 8; ++e) vals[e] = -1e30f;
    }
#pragma unroll
    for (int s = 1; s < 64; s <<= 1) m = fmaxf(m, __shfl_xor(m, s));
    float sum = 0.f;
#pragma unroll
    for (int e = 0; e < 8; ++e) {
        vals[e] = __expf(vals[e] - m);
        sum += vals[e];
    }
#pragma unroll
    for (int s = 1; s < 64; s <<= 1) sum += __shfl_xor(sum, s);
    const float inv = 1.f / sum;
    if (act) {
#pragma unroll
        for (int e = 0; e < 8; ++e) u.h[e] = __float2bfloat16(vals[e] * inv);
        *reinterpret_cast<uint4*>(rp + lane * 8) = u.v;
    }
}

// ---------------------------------------------------------------------------
// Batched P@V GEMM: ao[bh rows] = P[bh] @ Vt[bh]^T, causal K-limit:
// P[:, k >= m0+128] is exactly zero for rows in tile m0 -> K-loop to m0+128.
// N tile = 128 (cols 96..127 garbage, guarded). Writes ao [T,768] bf16.
// ---------------------------------------------------------------------------
__global__ __launch_bounds__(256, 3) void gemm_pv(
    const bf16_t* __restrict__ P, const bf16_t* __restrict__ Vt,
    bf16_t* __restrict__ ao) {
    const int bh = blockIdx.z;
    const int m0 = blockIdx.y * 128;
    const bf16_t* A = P + (size_t)bh * SS * SS;
    const bf16_t* W = Vt + (size_t)bh * 128 * SS;
    __shared__ uint4 As4[128 * 8];
    __shared__ uint4 Bs4[128 * 8];
    const int lane = threadIdx.x & 63, wave = threadIdx.x >> 6;
    const int wr = wave >> 1, wc = wave & 1;
    const int r = lane & 15, q = lane >> 4;
    const int K = SS;         // row stride of P / Vt
    const int kmax = m0 + 128;  // causal: P zero beyond this for all tile rows

    f32x4 acc[4][4];
#pragma unroll
    for (int i = 0; i < 4; ++i)
#pragma unroll
        for (int j = 0; j < 4; ++j) acc[i][j] = f32x4{0.f, 0.f, 0.f, 0.f};

    for (int k0 = 0; k0 < kmax; k0 += 64) {
#pragma unroll
        for (int it = 0; it < 4; ++it) {
            int base = it * 256 + wave * 64;
            int c = base + lane;
            int row = c >> 3, pc = c & 7;
            int kc = pc ^ (row & 7);
            load_lds16(A + (size_t)(m0 + row) * K + k0 + kc * 8, &As4[base]);
            load_lds16(W + (size_t)row * K + k0 + kc * 8, &Bs4[base]);
        }
        __syncthreads();
#pragma unroll
        for (int kk = 0; kk < 2; ++kk) {
            bf16x8 af[4], bfr[4];
            int lc = kk * 4 + q;
#pragma unroll
            for (int i = 0; i < 4; ++i) {
                int rowA = wr * 64 + i * 16 + r;
                af[i] = *reinterpret_cast<const bf16x8*>(&As4[rowA * 8 + (lc ^ (rowA & 7))]);
                int rowB = wc * 64 + i * 16 + r;
                bfr[i] = *reinterpret_cast<const bf16x8*>(&Bs4[rowB * 8 + (lc ^ (rowB & 7))]);
            }
#pragma unroll
            for (int i = 0; i < 4; ++i)
#pragma unroll
                for (int j = 0; j < 4; ++j)
                    acc[i][j] = __builtin_amdgcn_mfma_f32_16x16x32_bf16(af[i], bfr[j], acc[i][j], 0, 0, 0);
        }
        __syncthreads();
    }

    const int b = bh >> 3, hh = bh & 7;
#pragma unroll
    for (int i = 0; i < 4; ++i) {
#pragma unroll
        for (int j = 0; j < 4; ++j) {
            int cc = wc * 64 + j * 16 + r;  // head dim 0..127
            if (cc < DHH) {
#pragma unroll
                for (int reg = 0; reg < 4; ++reg) {
                    int s = m0 + wr * 64 + i * 16 + q * 4 + reg;
                    size_t t = (size_t)b * SS + s;
                    ao[t * DD + hh * DHH + cc] = __float2bfloat16(acc[i][j][reg]);
                }
            }
        }
    }
}

// ---------------------------------------------------------------------------
// LayerNorm over D=768. In-place safe.
// ---------------------------------------------------------------------------
__global__ __launch_bounds__(256) void ln_kernel(const float* __restrict__ in,
                                                 const float* __restrict__ g,
                                                 const float* __restrict__ beta,
                                                 float* __restrict__ xo,
                                                 bf16_t* __restrict__ xb) {
    const int row = blockIdx.x;
    const int tid = threadIdx.x;
    const float* ip = in + (size_t)row * DD;
    float v[3];
#pragma unroll
    for (int t = 0; t < 3; ++t) v[t] = ip[tid + t * 256];
    float s = v[0] + v[1] + v[2];
    float ss = v[0] * v[0] + v[1] * v[1] + v[2] * v[2];
    for (int off = 32; off > 0; off >>= 1) {
        s += __shfl_down(s, off);
        ss += __shfl_down(ss, off);
    }
    __shared__ float red[8];
    if ((tid & 63) == 0) {
        red[(tid >> 6) * 2] = s;
        red[(tid >> 6) * 2 + 1] = ss;
    }
    __syncthreads();
    s = red[0] + red[2] + red[4] + red[6];
    ss = red[1] + red[3] + red[5] + red[7];
    const float mean = s * (1.f / DD);
    const float var = ss * (1.f / DD) - mean * mean;
    const float rs = rsqrtf(var + 1e-5f);
#pragma unroll
    for (int t = 0; t < 3; ++t) {
        int d = tid + t * 256;
        float y = (v[t] - mean) * rs * g[d] + beta[d];
        xo[(size_t)row * DD + d] = y;
        xb[(size_t)row * DD + d] = __float2bfloat16(y);
    }
}

// ---------------------------------------------------------------------------
// Fused LN1 -> +cv broadcast -> LN2. Reads tmp once, writes x + xb once.
// ---------------------------------------------------------------------------
__global__ __launch_bounds__(256) void ln12_kernel(const float* __restrict__ in,
                                                   const float* __restrict__ cvv,
                                                   const float* __restrict__ g1,
                                                   const float* __restrict__ b1,
                                                   const float* __restrict__ g2,
                                                   const float* __restrict__ b2,
                                                   float* __restrict__ xo,
                                                   bf16_t* __restrict__ xb) {
    const int row = blockIdx.x;
    const int tid = threadIdx.x;
    const float* ip = in + (size_t)row * DD;
    const float* cp = cvv + (size_t)(row >> 9) * DD;
    __shared__ float red[8];
    float v[3];
#pragma unroll
    for (int t = 0; t < 3; ++t) v[t] = ip[tid + t * 256];
    // ---- LN1
    float s = v[0] + v[1] + v[2];
    float ss = v[0] * v[0] + v[1] * v[1] + v[2] * v[2];
    for (int off = 32; off > 0; off >>= 1) {
        s += __shfl_down(s, off);
        ss += __shfl_down(ss, off);
    }
    if ((tid & 63) == 0) {
        red[(tid >> 6) * 2] = s;
        red[(tid >> 6) * 2 + 1] = ss;
    }
    __syncthreads();
    s = red[0] + red[2] + red[4] + red[6];
    ss = red[1] + red[3] + red[5] + red[7];
    float mean = s * (1.f / DD);
    float var = ss * (1.f / DD) - mean * mean;
    float rs = rsqrtf(var + 1e-5f);
#pragma unroll
    for (int t = 0; t < 3; ++t) {
        int d = tid + t * 256;
        v[t] = (v[t] - mean) * rs * g1[d] + b1[d] + cp[d];
    }
    // ---- LN2
    s = v[0] + v[1] + v[2];
    ss = v[0] * v[0] + v[1] * v[1] + v[2] * v[2];
    for (int off = 32; off > 0; off >>= 1) {
        s += __shfl_down(s, off);
        ss += __shfl_down(ss, off);
    }
    __syncthreads();  // protect red reuse
    if ((tid & 63) == 0) {
        red[(tid >> 6) * 2] = s;
        red[(tid >> 6) * 2 + 1] = ss;
    }
    __syncthreads();
    s = red[0] + red[2] + red[4] + red[6];
    ss = red[1] + red[3] + red[5] + red[7];
    mean = s * (1.f / DD);
    var = ss * (1.f / DD) - mean * mean;
    rs = rsqrtf(var + 1e-5f);
#pragma unroll
    for (int t = 0; t < 3; ++t) {
        int d = tid + t * 256;
        float y = (v[t] - mean) * rs * g2[d] + b2[d];
        xo[(size_t)row * DD + d] = y;
        xb[(size_t)row * DD + d] = __float2bfloat16(y);
    }
}

// ---------------------------------------------------------------------------
// Host launcher
// ---------------------------------------------------------------------------
extern "C" void kernel_launch(void* const* d_in, const int* in_sizes, int n_in,
                              void* d_out, int out_size, void* d_ws, size_t ws_size,
                              hipStream_t stream) {
    (void)in_sizes; (void)n_in; (void)out_size; (void)ws_size;
    const float* latent   = (const float*)d_in[0];
    const int*   target   = (const int*)d_in[1];
    const float* tok_emb  = (const float*)d_in[2];
    const float* pos_emb  = (const float*)d_in[3];
    const float* sa_w_qkv = (const float*)d_in[4];
    const float* sa_b_qkv = (const float*)d_in[5];
    const float* sa_w_o   = (const float*)d_in[6];
    const float* sa_b_o   = (const float*)d_in[7];
    const float* ca_w_qkv = (const float*)d_in[8];
    const float* ca_b_qkv = (const float*)d_in[9];
    const float* ca_w_o   = (const float*)d_in[10];
    const float* ca_b_o   = (const float*)d_in[11];
    const float* ffn_w1   = (const float*)d_in[12];
    const float* ffn_b1   = (const float*)d_in[13];
    const float* ffn_w2   = (const float*)d_in[14];
    const float* ffn_b2   = (const float*)d_in[15];
    const float* ln1_g    = (const float*)d_in[16];
    const float* ln1_b    = (const float*)d_in[17];
    const float* ln2_g    = (const float*)d_in[18];
    const float* ln2_b    = (const float*)d_in[19];
    const float* ln3_g    = (const float*)d_in[20];
    const float* ln3_b    = (const float*)d_in[21];
    const float* out_w    = (const float*)d_in[22];
    const float* out_b    = (const float*)d_in[23];
    float* out = (float*)d_out;

    // workspace carve-up (256B aligned)
    char* ws = (char*)d_ws;
    size_t off = 0;
    auto alloc = [&](size_t bytes) {
        void* p = ws + off;
        off += (bytes + 255) & ~(size_t)255;
        return p;
    };
    float*  x    = (float*)alloc((size_t)TT * DD * 4);        // residual stream fp32
    bf16_t* xb   = (bf16_t*)alloc((size_t)TT * DD * 2);       // bf16 shadow
    bf16_t* ao   = (bf16_t*)alloc((size_t)TT * DD * 2);       // attn out bf16
    float*  cv   = (float*)alloc((size_t)LL * BB * DD * 4);   // cross-attn vectors
    float*  v16  = (float*)alloc((size_t)LL * BB * DD * 4);   // cv stage-1 temp
    bf16_t* wqkv_b = (bf16_t*)alloc((size_t)LL * 3 * DD * DD * 2);
    bf16_t* wo_b   = (bf16_t*)alloc((size_t)LL * DD * DD * 2);
    bf16_t* w1_b   = (bf16_t*)alloc((size_t)LL * FF * DD * 2);
    bf16_t* w2_b   = (bf16_t*)alloc((size_t)LL * DD * FF * 2);
    bf16_t* wout_b = (bf16_t*)alloc((size_t)128 * DD * 2);
    // Attention region:
    //   Qh [128][512][128] bf16 (16.78 MB)  zero-padded cols 96..127 (filled once)
    //   Kh [128][512][128] bf16 (16.78 MB)  zero-padded cols 96..127 (filled once)
    //   Vt [128][128][512] bf16 (16.78 MB)  rows 96..127 unused garbage (guarded)
    //   Scb[128][512][512] bf16 (67.1 MB)   scores, then P in place
    char* attnR = (char*)alloc((size_t)BH * SS * 128 * 2 * 3 + (size_t)BH * SS * SS * 2);
    bf16_t* Qh  = (bf16_t*)attnR;
    bf16_t* Kh  = Qh + (size_t)BH * SS * 128;
    bf16_t* Vt  = Kh + (size_t)BH * SS * 128;
    bf16_t* Scb = Vt + (size_t)BH * 128 * SS;
    // FFN-phase overlays go inside Scb ONLY (67.1 MB >= 33.6 + 25.2 MB).
    // Qh/Kh must never be overwritten: their zero pad columns are filled once
    // and reused across all layers. Stale upper-triangle data in Scb is
    // masked by the causal softmax / never read by the K-limited pv.
    bf16_t* h   = Scb;                                         // [T,2048] bf16 (33.6 MB)
    float*  tmp = (float*)((char*)Scb + ((size_t)34 << 20));   // [T,768] fp32 (25.2 MB)

    // weight conversions (every call: ws is re-poisoned)
    cvt_kernel<<<2048, 256, 0, stream>>>(sa_w_qkv, wqkv_b, LL * 3 * DD * DD);
    cvt_kernel<<<2048, 256, 0, stream>>>(sa_w_o, wo_b, LL * DD * DD);
    cvt_kernel<<<2048, 256, 0, stream>>>(ffn_w1, w1_b, LL * FF * DD);
    cvt_kernel<<<2048, 256, 0, stream>>>(ffn_w2, w2_b, LL * DD * FF);
    pad_wout_kernel<<<(128 * DD) / 256, 256, 0, stream>>>(out_w, wout_b);
    // zero Qh+Kh (pad columns 96..127 must be 0; zero both fully, once per call)
    {
        int n4 = (int)(((size_t)BH * SS * 128 * 2 * 2) / 16);  // uint4 count
        fill_zero_kernel<<<(n4 + 255) / 256, 256, 0, stream>>>((uint4*)Qh, n4);
    }

    // collapsed cross-attention: v16 = latent @ Wv^T + bv; cv = v16 @ Wo^T + bo
    cvmm_kernel<<<dim3(DD / 16, LL), 256, 0, stream>>>(
        latent, 0, ca_w_qkv, (size_t)3 * DD * DD, (size_t)2 * DD * DD,
        ca_b_qkv, (size_t)3 * DD, (size_t)2 * DD, v16);
    cvmm_kernel<<<dim3(DD / 16, LL), 256, 0, stream>>>(
        v16, BB * DD, ca_w_o, (size_t)DD * DD, 0,
        ca_b_o, (size_t)DD, 0, cv);

    // embeddings
    embed_kernel<<<TT, 256, 0, stream>>>(target, tok_emb, pos_emb, x, xb);

    for (int i = 0; i < LL; ++i) {
        // QKV projection -> Qh/Kh/Vt (head-major bf16, scale folded into Q)
        gemm_qkv<<<dim3(3 * DD / 128, TT / 128), 256, 0, stream>>>(
            xb, wqkv_b + (size_t)i * 3 * DD * DD, sa_b_qkv + (size_t)i * 3 * DD,
            Qh, Kh, Vt);
        // scores (lower-triangle tiles only)
        gemm_sc<<<dim3(4, 4, BH), 256, 0, stream>>>(Qh, Kh, Scb);
        // causal softmax in place -> P (bf16, zeros up to q-tile boundary)
        softmax_kernel<<<(BH * SS) / 4, 256, 0, stream>>>(Scb);
        // P @ V -> ao (causal K-limit)
        gemm_pv<<<dim3(1, 4, BH), 256, 0, stream>>>(Scb, Vt, ao);
        // O projection + residual -> tmp
        gemm_bt<false, false, true><<<dim3(DD / 128, TT / 128), 256, 0, stream>>>(
            ao, wo_b + (size_t)i * DD * DD, sa_b_o + (size_t)i * DD,
            x, tmp, nullptr, DD, DD, DD);
        // LN1 + cv + LN2 fused -> x, xb
        ln12_kernel<<<TT, 256, 0, stream>>>(tmp, cv + (size_t)i * BB * DD,
                                            ln1_g + (size_t)i * DD, ln1_b + (size_t)i * DD,
                                            ln2_g + (size_t)i * DD, ln2_b + (size_t)i * DD,
                                            x, xb);
        // FFN1: relu(x@W1^T+b1) -> h (bf16)
        gemm_bt<true, true, false><<<dim3(FF / 128, TT / 128), 256, 0, stream>>>(
            xb, w1_b + (size_t)i * FF * DD, ffn_b1 + (size_t)i * FF,
            nullptr, nullptr, h, DD, FF, FF);
        // FFN2 + residual -> tmp
        gemm_bt<false, false, true><<<dim3(DD / 128, TT / 128), 256, 0, stream>>>(
            h, w2_b + (size_t)i * DD * FF, ffn_b2 + (size_t)i * DD,
            x, tmp, nullptr, FF, DD, DD);
        // LN3 -> x, xb
        ln_kernel<<<TT, 256, 0, stream>>>(tmp, ln3_g + (size_t)i * DD,
                                          ln3_b + (size_t)i * DD, x, xb);
    }

    // final projection to logits [8192,100] (padded N=128, guarded)
    gemm_bt<false, false, false><<<dim3(1, TT / 128), 256, 0, stream>>>(
        xb, wout_b, out_b, nullptr, out, nullptr, DD, VV, VV);
}